// Round 12
// baseline (218.203 us; speedup 1.0000x reference)
//
#include <hip/hip_runtime.h>
#include <cstdint>

typedef __attribute__((ext_vector_type(8))) _Float16 half8;
typedef __attribute__((ext_vector_type(4))) _Float16 half4;
typedef __attribute__((ext_vector_type(2))) __fp16 fp16x2;
typedef __attribute__((ext_vector_type(4))) float f32x4;

union H8 { half8 v; unsigned u[4]; };
union H2U { fp16x2 h; unsigned u; };

__device__ __forceinline__ void gld_lds16(const void* g, void* l) {
  __builtin_amdgcn_global_load_lds(
      (const __attribute__((address_space(1))) unsigned int*)g,
      (__attribute__((address_space(3))) unsigned int*)l, 16, 0, 0);
}

// ---------------- fused cast fp32 -> fp16 (x | qkv_w | proj_w) ----------------
__global__ __launch_bounds__(256) void cast3_kernel(
    const float* __restrict__ x, const float* __restrict__ w1,
    const float* __restrict__ w2, _Float16* __restrict__ out) {
  int i = blockIdx.x * 256 + threadIdx.x;   // chunk of 4 floats
  const float* src;
  int off;
  if (i < 1048576)      { src = x;  off = i; }
  else if (i < 1835008) { src = w1; off = i - 1048576; }
  else                  { src = w2; off = i - 1835008; }
  float4 v = ((const float4*)src)[off];
  half4 h;
  h[0] = (_Float16)v.x; h[1] = (_Float16)v.y;
  h[2] = (_Float16)v.z; h[3] = (_Float16)v.w;
  ((half4*)out)[i] = h;
}

// ---------------- GEMM: C[M,N] = A[M,K] * B[N,K]^T (unchanged from r11) ----------------
template <int EPI>
__global__ __launch_bounds__(256) void gemm_bt(
    const _Float16* __restrict__ A, const _Float16* __restrict__ B, int K,
    _Float16* __restrict__ Qb, _Float16* __restrict__ Kb, _Float16* __restrict__ VbT,
    float* __restrict__ Out, const float* __restrict__ Bias) {
  __shared__ _Float16 Asm[2][128 * 32];
  __shared__ _Float16 Bsm[2][128 * 32];
  const int tid = threadIdx.x;
  const int wave = tid >> 6, lane = tid & 63;
  const int l16 = lane & 15, lg = lane >> 4;
  const int m0 = blockIdx.y * 128, n0 = blockIdx.x * 128;
  const int wr = wave >> 1, wc = wave & 1;
  f32x4 acc[4][4] = {};

  const int d0 = tid, d1 = tid + 256;
  const int row0 = d0 >> 2, cc0 = (d0 & 3) ^ ((row0 >> 1) & 3);
  const int row1 = d1 >> 2, cc1 = (d1 & 3) ^ ((row1 >> 1) & 3);
  const int sread = ((lg ^ ((l16 >> 1) & 3))) * 16;

  auto STAGE = [&](int buf, int k0) {
    gld_lds16(A + (size_t)(m0 + row0) * K + k0 + cc0 * 8, (char*)Asm[buf] + d0 * 16);
    gld_lds16(A + (size_t)(m0 + row1) * K + k0 + cc1 * 8, (char*)Asm[buf] + d1 * 16);
    gld_lds16(B + (size_t)(n0 + row0) * K + k0 + cc0 * 8, (char*)Bsm[buf] + d0 * 16);
    gld_lds16(B + (size_t)(n0 + row1) * K + k0 + cc1 * 8, (char*)Bsm[buf] + d1 * 16);
  };

  STAGE(0, 0);
  int cur = 0;
  for (int k0 = 0; k0 < K; k0 += 32) {
    __syncthreads();
    if (k0 + 32 < K) STAGE(cur ^ 1, k0 + 32);
    const char* Ac = (const char*)Asm[cur];
    const char* Bc = (const char*)Bsm[cur];
    half8 af[4], bf[4];
#pragma unroll
    for (int f = 0; f < 4; f++) {
      af[f] = *(const half8*)(Ac + (wr * 64 + f * 16 + l16) * 64 + sread);
      bf[f] = *(const half8*)(Bc + (wc * 64 + f * 16 + l16) * 64 + sread);
    }
#pragma unroll
    for (int i = 0; i < 4; i++)
#pragma unroll
      for (int j = 0; j < 4; j++)
        acc[i][j] = __builtin_amdgcn_mfma_f32_16x16x32_f16(af[i], bf[j], acc[i][j], 0, 0, 0);
    cur ^= 1;
  }

  if (EPI == 0) {
#pragma unroll
    for (int i = 0; i < 4; i++) {
      int mbase = m0 + wr * 64 + i * 16 + lg * 4;    // 4-aligned
      int b = mbase >> 11, s = mbase & 2047;
#pragma unroll
      for (int j = 0; j < 4; j++) {
        int n = n0 + wc * 64 + j * 16 + l16;
        int part = n >> 10, f = n & 1023;
        int h = f >> 6, d = f & 63;
        if (part == 2) {
          int x = s & 31;
          int sp = (s & ~31) | (((x >> 2) & 3) << 3) | (((x >> 4) & 1) << 2);
          half4 v;
          v[0] = (_Float16)acc[i][j][0]; v[1] = (_Float16)acc[i][j][1];
          v[2] = (_Float16)acc[i][j][2]; v[3] = (_Float16)acc[i][j][3];
          *(half4*)(VbT + (((size_t)b * 16 + h) * 64 + d) * 2048 + sp) = v;
        } else {
          _Float16* dst = (part == 0) ? Qb : Kb;
          // Q pre-scale: 1/sqrt(64) * log2(e)
          float scale = (part == 0) ? 0.18033688f : 1.0f;
#pragma unroll
          for (int r = 0; r < 4; r++)
            dst[(((size_t)b * 16 + h) * 2048 + (s + r)) * 64 + d] =
                (_Float16)(acc[i][j][r] * scale);
        }
      }
    }
  } else {
#pragma unroll
    for (int i = 0; i < 4; i++) {
      int mbase = m0 + wr * 64 + i * 16 + lg * 4;
#pragma unroll
      for (int j = 0; j < 4; j++) {
        int n = n0 + wc * 64 + j * 16 + l16;
        float bias = Bias[n];
#pragma unroll
        for (int r = 0; r < 4; r++) {
          int m = mbase + r;
          Out[(size_t)m * 1024 + n] = acc[i][j][r] + bias;
        }
      }
    }
  }
}

// ---------------- flash attention (prefix-causal), v8 ----------------
// grid (32 bh, 64 qtiles reversed); block 128 = 2 waves x 16 q-rows; KVBLK=64.
// K double-buffered in LDS (16KB); V fragments read DIRECT from global
// (j-permuted VbT = linear B-fragment; addresses independent of softmax ->
// latency hidden by exp/pack + TLP). Fixed-base exp2 softmax (Q pre-scaled).
__global__ __launch_bounds__(128) void attn_kernel(
    const _Float16* __restrict__ Qb, const _Float16* __restrict__ Kb,
    const _Float16* __restrict__ VbT, _Float16* __restrict__ AO) {
  __shared__ _Float16 Ks[2][64 * 64];
  const int bh = blockIdx.x;
  const int q0 = (63 - blockIdx.y) * 32;   // heaviest blocks first
  const int tid = threadIdx.x, wave = tid >> 6, lane = tid & 63;
  const int l16 = lane & 15, lg = lane >> 4;
  const int qw = q0 + wave * 16;
  const size_t bhbase = (size_t)bh * 2048 * 64;
  const _Float16* Kbb = Kb + bhbase;

  // K staging: 512 chunks of 16B over 128 threads -> 4 each; XOR pre-swizzle
  int kofs[4], cdst[4];
#pragma unroll
  for (int i = 0; i < 4; i++) {
    int c = tid + i * 128;
    cdst[i] = c;
    kofs[i] = ((c >> 3) * 64) + (((c & 7) ^ ((c >> 3) & 7)) * 8);
  }

  // Q fragments (B-operand rows q = qw + l16)
  half8 qf[2];
#pragma unroll
  for (int kc = 0; kc < 2; kc++)
    qf[kc] = *(const half8*)(Qb + bhbase + (size_t)(qw + l16) * 64 + kc * 32 + lg * 8);

  // per-lane V base (row d = l16 within each db-block of 16)
  const _Float16* Vl = VbT + bhbase + (size_t)l16 * 2048 + lg * 8;

  f32x4 oacc[4] = {};
  float lrun = 0.f;                        // per-lane partial, reduced at end
  int kend = (q0 + 32 + 63) & ~63;
  if (kend < 256) kend = 256;

  const int xv = (l16 & 7) << 4;
  const int rb0 = l16 * 128 + ((lg * 16) ^ xv);
  const int rb1 = l16 * 128 + ((64 + lg * 16) ^ xv);

  auto STAGE = [&](int buf, int j0) {
#pragma unroll
    for (int i = 0; i < 4; i++)
      gld_lds16(Kbb + j0 * 64 + kofs[i], (char*)Ks[buf] + cdst[i] * 16);
  };

  STAGE(0, 0);
  int cur = 0;
  for (int j0 = 0; j0 < kend; j0 += 64) {
    __syncthreads();   // vmcnt(0) drain = wait for cur's K stage; barrier
    if (j0 + 64 < kend) STAGE(cur ^ 1, j0 + 64);
    const char* Kc = (const char*)Ks[cur];

    // S^T = K Q^T : lane holds S[q = qw+l16][j = j0+jb*16+lg*4+r] (log2 units)
    f32x4 sf[4] = {};
    __builtin_amdgcn_s_setprio(1);
#pragma unroll
    for (int kc = 0; kc < 2; kc++) {
      const int rb = kc ? rb1 : rb0;
#pragma unroll
      for (int jb = 0; jb < 4; jb++) {
        half8 kf = *(const half8*)(Kc + jb * 2048 + rb);
        sf[jb] = __builtin_amdgcn_mfma_f32_16x16x32_f16(kf, qf[kc], sf[jb], 0, 0, 0);
      }
    }
    __builtin_amdgcn_s_setprio(0);

    // issue V fragment loads early (independent of softmax; L2-served)
    half8 vf[2][4];
#pragma unroll
    for (int kc = 0; kc < 2; kc++)
#pragma unroll
      for (int db = 0; db < 4; db++)
        vf[kc][db] = *(const half8*)(Vl + (size_t)(db * 16) * 2048 + j0 + kc * 32);

    // prefix-causal mask: visible iff j <= s || j < 256
    if (j0 + 63 >= 256 && j0 + 63 > qw) {
      const int stok = qw + l16;
#pragma unroll
      for (int jb = 0; jb < 4; jb++)
#pragma unroll
        for (int r = 0; r < 4; r++) {
          int j = j0 + jb * 16 + lg * 4 + r;
          if (j > stok && j >= 256) sf[jb][r] = -1e30f;
        }
    }

    // P = exp2(S) (fixed base; scores bounded so fp16 P <= ~2^11 safe)
    float p[16];
#pragma unroll
    for (int jb = 0; jb < 4; jb++)
#pragma unroll
      for (int r = 0; r < 4; r++)
        p[jb * 4 + r] = exp2f(sf[jb][r]);

    float s0 = (p[0] + p[1]) + (p[2] + p[3]);
    float s1 = (p[4] + p[5]) + (p[6] + p[7]);
    float s2 = (p[8] + p[9]) + (p[10] + p[11]);
    float s3 = (p[12] + p[13]) + (p[14] + p[15]);
    lrun += (s0 + s1) + (s2 + s3);

    // pack P to fp16; permuted-j layout makes this the exact B-fragment
    H8 pf[2];
#pragma unroll
    for (int kc = 0; kc < 2; kc++) {
      H2U t0, t1, t2, t3;
      t0.h = __builtin_amdgcn_cvt_pkrtz(p[kc * 8 + 0], p[kc * 8 + 1]);
      t1.h = __builtin_amdgcn_cvt_pkrtz(p[kc * 8 + 2], p[kc * 8 + 3]);
      t2.h = __builtin_amdgcn_cvt_pkrtz(p[kc * 8 + 4], p[kc * 8 + 5]);
      t3.h = __builtin_amdgcn_cvt_pkrtz(p[kc * 8 + 6], p[kc * 8 + 7]);
      pf[kc].u[0] = t0.u; pf[kc].u[1] = t1.u;
      pf[kc].u[2] = t2.u; pf[kc].u[3] = t3.u;
    }

    // O^T += V^T P : lane holds O[q = qw+l16][d = db*16+lg*4+r]
    __builtin_amdgcn_s_setprio(1);
#pragma unroll
    for (int kc = 0; kc < 2; kc++)
#pragma unroll
      for (int db = 0; db < 4; db++)
        oacc[db] = __builtin_amdgcn_mfma_f32_16x16x32_f16(vf[kc][db], pf[kc].v, oacc[db], 0, 0, 0);
    __builtin_amdgcn_s_setprio(0);
    cur ^= 1;
  }

  // final lrun reduce (deferred from the loop)
  lrun += __shfl_xor(lrun, 16);
  lrun += __shfl_xor(lrun, 32);

  const int b = bh >> 4, h = bh & 15;
  float inv = 1.0f / lrun;
  int q = qw + l16;
#pragma unroll
  for (int db = 0; db < 4; db++) {
    half4 o;
    o[0] = (_Float16)(oacc[db][0] * inv);
    o[1] = (_Float16)(oacc[db][1] * inv);
    o[2] = (_Float16)(oacc[db][2] * inv);
    o[3] = (_Float16)(oacc[db][3] * inv);
    *(half4*)(AO + ((size_t)b * 2048 + q) * 1024 + h * 64 + db * 16 + lg * 4) = o;
  }
}

// ---------------- launch ----------------
extern "C" void kernel_launch(void* const* d_in, const int* in_sizes, int n_in,
                              void* d_out, int out_size, void* d_ws, size_t ws_size,
                              hipStream_t stream) {
  const float* x      = (const float*)d_in[0];  // (2,2048,1024)
  const float* qkv_w  = (const float*)d_in[1];  // (3072,1024)
  const float* proj_w = (const float*)d_in[2];  // (1024,1024)
  const float* proj_b = (const float*)d_in[3];  // (1024,)
  float* out = (float*)d_out;

  char* ws = (char*)d_ws;
  _Float16* Xh  = (_Float16*)(ws);                      // 4096x1024
  _Float16* Wq  = (_Float16*)(ws + ((size_t)8 << 20));  // 3072x1024
  _Float16* Wp  = (_Float16*)(ws + ((size_t)14 << 20)); // 1024x1024
  _Float16* Qb  = (_Float16*)(ws + ((size_t)16 << 20)); // 32x2048x64
  _Float16* Kb  = (_Float16*)(ws + ((size_t)24 << 20));
  _Float16* VbT = (_Float16*)(ws + ((size_t)32 << 20)); // 32x64x2048 (transposed, j-permuted)
  _Float16* AO  = (_Float16*)(ws + ((size_t)40 << 20)); // 4096x1024

  cast3_kernel<<<8192, 256, 0, stream>>>(x, qkv_w, proj_w, Xh);

  gemm_bt<0><<<dim3(24, 32), 256, 0, stream>>>(Xh, Wq, 1024, Qb, Kb, VbT, nullptr, nullptr);
  attn_kernel<<<dim3(32, 64), 128, 0, stream>>>(Qb, Kb, VbT, AO);
  gemm_bt<1><<<dim3(8, 32), 256, 0, stream>>>(AO, Wp, 1024, nullptr, nullptr, nullptr, out, proj_b);
}

// Round 13
// 191.151 us; speedup vs baseline: 1.1415x; 1.1415x over previous
//
#include <hip/hip_runtime.h>
#include <cstdint>

typedef __attribute__((ext_vector_type(8))) _Float16 half8;
typedef __attribute__((ext_vector_type(4))) _Float16 half4;
typedef __attribute__((ext_vector_type(2))) __fp16 fp16x2;
typedef __attribute__((ext_vector_type(4))) float f32x4;

union H8 { half8 v; unsigned u[4]; };
union H2U { fp16x2 h; unsigned u; };

__device__ __forceinline__ void gld_lds16(const void* g, void* l) {
  __builtin_amdgcn_global_load_lds(
      (const __attribute__((address_space(1))) unsigned int*)g,
      (__attribute__((address_space(3))) unsigned int*)l, 16, 0, 0);
}

// ---------------- fused cast fp32 -> fp16 (x | qkv_w | proj_w) ----------------
__global__ __launch_bounds__(256) void cast3_kernel(
    const float* __restrict__ x, const float* __restrict__ w1,
    const float* __restrict__ w2, _Float16* __restrict__ out) {
  int i = blockIdx.x * 256 + threadIdx.x;   // chunk of 4 floats
  const float* src;
  int off;
  if (i < 1048576)      { src = x;  off = i; }
  else if (i < 1835008) { src = w1; off = i - 1048576; }
  else                  { src = w2; off = i - 1835008; }
  float4 v = ((const float4*)src)[off];
  half4 h;
  h[0] = (_Float16)v.x; h[1] = (_Float16)v.y;
  h[2] = (_Float16)v.z; h[3] = (_Float16)v.w;
  ((half4*)out)[i] = h;
}

// ---------------- GEMM: C[M,N] = A[M,K] * B[N,K]^T ----------------
// Tile TM x TN, BK=32, double-buffered LDS, 4 waves as 2x2 (wave tile TM/2 x TN/2).
// Grid sized for >=4 blocks/CU (latency-bound fix, r12).
// EPI 0: scatter Q(*0.125*log2e)/K to [bh][s][64]; V^T j-permuted to [bh][d][s']
// EPI 1: fp32 out + bias
template <int TM, int TN, int EPI>
__global__ __launch_bounds__(256) void gemm_bt(
    const _Float16* __restrict__ A, const _Float16* __restrict__ B, int K,
    _Float16* __restrict__ Qb, _Float16* __restrict__ Kb, _Float16* __restrict__ VbT,
    float* __restrict__ Out, const float* __restrict__ Bias) {
  constexpr int NA = TM * 4 / 256;   // A 16B-chunks per thread
  constexpr int NB = TN * 4 / 256;   // B 16B-chunks per thread
  constexpr int FM = TM / 32;        // A fragments per wave
  constexpr int FN = TN / 32;        // B fragments per wave
  __shared__ _Float16 Asm[2][TM * 32];
  __shared__ _Float16 Bsm[2][TN * 32];
  const int tid = threadIdx.x;
  const int wave = tid >> 6, lane = tid & 63;
  const int l16 = lane & 15, lg = lane >> 4;
  const int m0 = blockIdx.y * TM, n0 = blockIdx.x * TN;
  const int wr = wave >> 1, wc = wave & 1;
  f32x4 acc[FM][FN] = {};

  // staging: lane-linear LDS dest, swizzled global chunk cc ^= (row>>1)&3
  int arow[NA], acc_[NA], brow[NB], bcc[NB];
#pragma unroll
  for (int i = 0; i < NA; i++) {
    int c = tid + i * 256;
    arow[i] = c >> 2; acc_[i] = ((c & 3) ^ ((arow[i] >> 1) & 3)) * 8;
  }
#pragma unroll
  for (int i = 0; i < NB; i++) {
    int c = tid + i * 256;
    brow[i] = c >> 2; bcc[i] = ((c & 3) ^ ((brow[i] >> 1) & 3)) * 8;
  }
  const int sread = (lg ^ ((l16 >> 1) & 3)) * 16;

  auto STAGE = [&](int buf, int k0) {
#pragma unroll
    for (int i = 0; i < NA; i++)
      gld_lds16(A + (size_t)(m0 + arow[i]) * K + k0 + acc_[i],
                (char*)Asm[buf] + (tid + i * 256) * 16);
#pragma unroll
    for (int i = 0; i < NB; i++)
      gld_lds16(B + (size_t)(n0 + brow[i]) * K + k0 + bcc[i],
                (char*)Bsm[buf] + (tid + i * 256) * 16);
  };

  STAGE(0, 0);
  int cur = 0;
  for (int k0 = 0; k0 < K; k0 += 32) {
    __syncthreads();                       // drains cur's stage
    if (k0 + 32 < K) STAGE(cur ^ 1, k0 + 32);
    const char* Ac = (const char*)Asm[cur];
    const char* Bc = (const char*)Bsm[cur];
    half8 af[FM], bf[FN];
#pragma unroll
    for (int f = 0; f < FM; f++)
      af[f] = *(const half8*)(Ac + (wr * (TM / 2) + f * 16 + l16) * 64 + sread);
#pragma unroll
    for (int g = 0; g < FN; g++)
      bf[g] = *(const half8*)(Bc + (wc * (TN / 2) + g * 16 + l16) * 64 + sread);
#pragma unroll
    for (int i = 0; i < FM; i++)
#pragma unroll
      for (int j = 0; j < FN; j++)
        acc[i][j] = __builtin_amdgcn_mfma_f32_16x16x32_f16(af[i], bf[j], acc[i][j], 0, 0, 0);
    cur ^= 1;
  }

  if (EPI == 0) {
#pragma unroll
    for (int i = 0; i < FM; i++) {
      int mbase = m0 + wr * (TM / 2) + i * 16 + lg * 4;    // 4-aligned
      int b = mbase >> 11, s = mbase & 2047;
#pragma unroll
      for (int j = 0; j < FN; j++) {
        int n = n0 + wc * (TN / 2) + j * 16 + l16;
        int part = n >> 10, f = n & 1023;
        int h = f >> 6, d = f & 63;
        if (part == 2) {
          int x = s & 31;
          int sp = (s & ~31) | (((x >> 2) & 3) << 3) | (((x >> 4) & 1) << 2);
          half4 v;
          v[0] = (_Float16)acc[i][j][0]; v[1] = (_Float16)acc[i][j][1];
          v[2] = (_Float16)acc[i][j][2]; v[3] = (_Float16)acc[i][j][3];
          *(half4*)(VbT + (((size_t)b * 16 + h) * 64 + d) * 2048 + sp) = v;
        } else {
          _Float16* dst = (part == 0) ? Qb : Kb;
          // Q pre-scale: 1/sqrt(64) * log2(e)
          float scale = (part == 0) ? 0.18033688f : 1.0f;
#pragma unroll
          for (int r = 0; r < 4; r++)
            dst[(((size_t)b * 16 + h) * 2048 + (s + r)) * 64 + d] =
                (_Float16)(acc[i][j][r] * scale);
        }
      }
    }
  } else {
#pragma unroll
    for (int i = 0; i < FM; i++) {
      int mbase = m0 + wr * (TM / 2) + i * 16 + lg * 4;
#pragma unroll
      for (int j = 0; j < FN; j++) {
        int n = n0 + wc * (TN / 2) + j * 16 + l16;
        float bias = Bias[n];
#pragma unroll
        for (int r = 0; r < 4; r++) {
          int m = mbase + r;
          Out[(size_t)m * 1024 + n] = acc[i][j][r] + bias;
        }
      }
    }
  }
}

// ---------------- flash attention (prefix-causal), v7 (r11 measured-best) ----------------
// grid (32 bh, 32 qtiles reversed); block 256 = 4 waves x 16 q-rows; KVBLK=64.
// K,V double-buffered LDS via global_load_lds (pre-swizzled source); swapped
// QK^T; fixed-base exp2 softmax (Q pre-scaled by log2e); P in regs.
__global__ __launch_bounds__(256) void attn_kernel(
    const _Float16* __restrict__ Qb, const _Float16* __restrict__ Kb,
    const _Float16* __restrict__ VbT, _Float16* __restrict__ AO) {
  __shared__ _Float16 Ks[2][64 * 64];
  __shared__ _Float16 Vt[2][64 * 64];
  const int bh = blockIdx.x;
  const int q0 = (31 - blockIdx.y) * 64;   // heaviest blocks first
  const int tid = threadIdx.x, wave = tid >> 6, lane = tid & 63;
  const int l16 = lane & 15, lg = lane >> 4;
  const int qw = q0 + wave * 16;
  const size_t bhbase = (size_t)bh * 2048 * 64;
  const _Float16* Kbb = Kb + bhbase;
  const _Float16* Vbb = VbT + bhbase;

  const int c0 = tid, c1 = tid + 256;
  const int kofs0 = ((c0 >> 3) * 64) + (((c0 & 7) ^ ((c0 >> 3) & 7)) * 8);
  const int kofs1 = ((c1 >> 3) * 64) + (((c1 & 7) ^ ((c1 >> 3) & 7)) * 8);
  const int vofs0 = ((c0 >> 3) * 2048) + (((c0 & 7) ^ ((c0 >> 3) & 7)) * 8);
  const int vofs1 = ((c1 >> 3) * 2048) + (((c1 & 7) ^ ((c1 >> 3) & 7)) * 8);

  half8 qf[2];
#pragma unroll
  for (int kc = 0; kc < 2; kc++)
    qf[kc] = *(const half8*)(Qb + bhbase + (size_t)(qw + l16) * 64 + kc * 32 + lg * 8);

  f32x4 oacc[4] = {};
  float lrun = 0.f;                        // per-lane partial, reduced at end
  const int kend = (q0 + 64 > 256) ? (q0 + 64) : 256;

  const int xv = (l16 & 7) << 4;
  const int rb0 = l16 * 128 + ((lg * 16) ^ xv);
  const int rb1 = l16 * 128 + ((64 + lg * 16) ^ xv);

  auto STAGE = [&](int buf, int j0) {
    gld_lds16(Kbb + j0 * 64 + kofs0, (char*)Ks[buf] + c0 * 16);
    gld_lds16(Kbb + j0 * 64 + kofs1, (char*)Ks[buf] + c1 * 16);
    gld_lds16(Vbb + j0 + vofs0, (char*)Vt[buf] + c0 * 16);
    gld_lds16(Vbb + j0 + vofs1, (char*)Vt[buf] + c1 * 16);
  };

  STAGE(0, 0);
  int cur = 0;
  for (int j0 = 0; j0 < kend; j0 += 64) {
    __syncthreads();   // vmcnt(0) drain = wait for cur's stage; barrier
    if (j0 + 64 < kend) STAGE(cur ^ 1, j0 + 64);
    const char* Kc = (const char*)Ks[cur];
    const char* Vc = (const char*)Vt[cur];

    // S^T = K Q^T : lane holds S[q = qw+l16][j = j0+jb*16+lg*4+r] (log2 units)
    f32x4 sf[4] = {};
    __builtin_amdgcn_s_setprio(1);
#pragma unroll
    for (int kc = 0; kc < 2; kc++) {
      const int rb = kc ? rb1 : rb0;
#pragma unroll
      for (int jb = 0; jb < 4; jb++) {
        half8 kf = *(const half8*)(Kc + jb * 2048 + rb);
        sf[jb] = __builtin_amdgcn_mfma_f32_16x16x32_f16(kf, qf[kc], sf[jb], 0, 0, 0);
      }
    }
    __builtin_amdgcn_s_setprio(0);

    // prefix-causal mask: visible iff j <= s || j < 256
    if (j0 + 63 >= 256 && j0 + 63 > qw) {
      const int stok = qw + l16;
#pragma unroll
      for (int jb = 0; jb < 4; jb++)
#pragma unroll
        for (int r = 0; r < 4; r++) {
          int j = j0 + jb * 16 + lg * 4 + r;
          if (j > stok && j >= 256) sf[jb][r] = -1e30f;
        }
    }

    // P = exp2(S) (fixed base; scores bounded so fp16 P <= ~2^11 safe)
    float p[16];
#pragma unroll
    for (int jb = 0; jb < 4; jb++)
#pragma unroll
      for (int r = 0; r < 4; r++)
        p[jb * 4 + r] = exp2f(sf[jb][r]);

    float s0 = (p[0] + p[1]) + (p[2] + p[3]);
    float s1 = (p[4] + p[5]) + (p[6] + p[7]);
    float s2 = (p[8] + p[9]) + (p[10] + p[11]);
    float s3 = (p[12] + p[13]) + (p[14] + p[15]);
    lrun += (s0 + s1) + (s2 + s3);

    // pack P to fp16; permuted-j layout makes this the exact B-fragment
    H8 pf[2];
#pragma unroll
    for (int kc = 0; kc < 2; kc++) {
      H2U t0, t1, t2, t3;
      t0.h = __builtin_amdgcn_cvt_pkrtz(p[kc * 8 + 0], p[kc * 8 + 1]);
      t1.h = __builtin_amdgcn_cvt_pkrtz(p[kc * 8 + 2], p[kc * 8 + 3]);
      t2.h = __builtin_amdgcn_cvt_pkrtz(p[kc * 8 + 4], p[kc * 8 + 5]);
      t3.h = __builtin_amdgcn_cvt_pkrtz(p[kc * 8 + 6], p[kc * 8 + 7]);
      pf[kc].u[0] = t0.u; pf[kc].u[1] = t1.u;
      pf[kc].u[2] = t2.u; pf[kc].u[3] = t3.u;
    }

    // O^T += V^T P : lane holds O[q = qw+l16][d = db*16+lg*4+r]
    __builtin_amdgcn_s_setprio(1);
#pragma unroll
    for (int kc = 0; kc < 2; kc++) {
      const int rb = kc ? rb1 : rb0;
#pragma unroll
      for (int db = 0; db < 4; db++) {
        half8 vf = *(const half8*)(Vc + db * 2048 + rb);
        oacc[db] = __builtin_amdgcn_mfma_f32_16x16x32_f16(vf, pf[kc].v, oacc[db], 0, 0, 0);
      }
    }
    __builtin_amdgcn_s_setprio(0);
    cur ^= 1;
  }

  // final lrun reduce (deferred from the loop)
  lrun += __shfl_xor(lrun, 16);
  lrun += __shfl_xor(lrun, 32);

  const int b = bh >> 4, h = bh & 15;
  float inv = 1.0f / lrun;
  int q = qw + l16;
#pragma unroll
  for (int db = 0; db < 4; db++) {
    half4 o;
    o[0] = (_Float16)(oacc[db][0] * inv);
    o[1] = (_Float16)(oacc[db][1] * inv);
    o[2] = (_Float16)(oacc[db][2] * inv);
    o[3] = (_Float16)(oacc[db][3] * inv);
    *(half4*)(AO + ((size_t)b * 2048 + q) * 1024 + h * 64 + db * 16 + lg * 4) = o;
  }
}

// ---------------- launch ----------------
extern "C" void kernel_launch(void* const* d_in, const int* in_sizes, int n_in,
                              void* d_out, int out_size, void* d_ws, size_t ws_size,
                              hipStream_t stream) {
  const float* x      = (const float*)d_in[0];  // (2,2048,1024)
  const float* qkv_w  = (const float*)d_in[1];  // (3072,1024)
  const float* proj_w = (const float*)d_in[2];  // (1024,1024)
  const float* proj_b = (const float*)d_in[3];  // (1024,)
  float* out = (float*)d_out;

  char* ws = (char*)d_ws;
  _Float16* Xh  = (_Float16*)(ws);                      // 4096x1024
  _Float16* Wq  = (_Float16*)(ws + ((size_t)8 << 20));  // 3072x1024
  _Float16* Wp  = (_Float16*)(ws + ((size_t)14 << 20)); // 1024x1024
  _Float16* Qb  = (_Float16*)(ws + ((size_t)16 << 20)); // 32x2048x64
  _Float16* Kb  = (_Float16*)(ws + ((size_t)24 << 20));
  _Float16* VbT = (_Float16*)(ws + ((size_t)32 << 20)); // 32x64x2048 (transposed, j-permuted)
  _Float16* AO  = (_Float16*)(ws + ((size_t)40 << 20)); // 4096x1024

  cast3_kernel<<<8192, 256, 0, stream>>>(x, qkv_w, proj_w, Xh);

  gemm_bt<128, 64, 0><<<dim3(48, 32), 256, 0, stream>>>(Xh, Wq, 1024, Qb, Kb, VbT, nullptr, nullptr);
  attn_kernel<<<dim3(32, 32), 256, 0, stream>>>(Qb, Kb, VbT, AO);
  gemm_bt<64, 64, 1><<<dim3(16, 64), 256, 0, stream>>>(AO, Wp, 1024, nullptr, nullptr, nullptr, out, proj_b);
}